// Round 6
// baseline (285.278 us; speedup 1.0000x reference)
//
#include <hip/hip_runtime.h>
#include <cstdint>

typedef __attribute__((ext_vector_type(8))) short short8;
typedef __attribute__((ext_vector_type(4))) float floatx4;

#define TWO_PI 6.283185307179586f

__device__ __forceinline__ unsigned short f2bf(float f) {
  union { float f; uint32_t u; } c; c.f = f;
  uint32_t u = c.u;
  u += 0x7FFFu + ((u >> 16) & 1u);   // RNE
  return (unsigned short)(u >> 16);
}
__device__ __forceinline__ uint32_t packbf(float re, float im) {
  return (uint32_t)f2bf(re) | ((uint32_t)f2bf(im) << 16);
}

// ---------------------------------------------------------------------------
// Four-step DFT convolution, N = 65536 = 256 x 256, t = c + 256 r, k = k1 + 256 k2.
// z_s = x[2s] + i x[2s+1].  All 256-pt DFT stages are real bf16 MFMA GEMMs via
// the 2x2 rotation embedding.  Stages 2+3 are FUSED (P-tile lives in LDS).
// ---------------------------------------------------------------------------

// Merged prep: blocks [0,3072) build A1..A4; [3072,4096) transpose/pack x->Zp;
// [4096,4352) compute Gw[k1][c] (root-table inner loop); [4352,4608) Tw[k1][c].
__global__ __launch_bounds__(256) void prep_all(
    const float* __restrict__ x, const float* __restrict__ filt,
    unsigned short* __restrict__ A1, unsigned short* __restrict__ A2,
    unsigned short* __restrict__ A3, unsigned short* __restrict__ A4,
    uint32_t* __restrict__ Zp, float2* __restrict__ Gw,
    float2* __restrict__ Tw) {
  __shared__ float2 roots[256];
  const int bid = blockIdx.x;
  const int tid = threadIdx.x;
  const float w256 = TWO_PI / 256.0f;
  if (bid < 3072) {
    int idx = bid * 256 + tid;
    if (idx < 131072) {                       // A1 [512x256], E-(k1 r/256)
      int col = idx & 255, row = idx >> 8;
      int k1 = row >> 1, d = row & 1, r = col >> 1, e = col & 1;
      float th = (float)((k1 * r) & 255) * w256;
      float sn, cs; __sincosf(th, &sn, &cs);
      A1[idx] = f2bf(d == 0 ? (e == 0 ? cs : sn) : (e == 0 ? -sn : cs));
    } else if (idx < 393216) {                // A2 [512x512], E-(k2 c/256)
      int j = idx - 131072;
      int col = j & 511, row = j >> 9;
      int k2 = row >> 1, d = row & 1, cc = col >> 1, e = col & 1;
      float th = (float)((k2 * cc) & 255) * w256;
      float sn, cs; __sincosf(th, &sn, &cs);
      A2[j] = f2bf(d == 0 ? (e == 0 ? cs : sn) : (e == 0 ? -sn : cs));
    } else if (idx < 655360) {                // A3 [512x512], rows 2c+d, E+(k2 c/256)
      int j = idx - 393216;
      int col = j & 511, row = j >> 9;
      int cc = row >> 1, d = row & 1, k2 = col >> 1, e = col & 1;
      float th = (float)((k2 * cc) & 255) * w256;
      float sn, cs; __sincosf(th, &sn, &cs);
      A3[j] = f2bf(d == 0 ? (e == 0 ? cs : -sn) : (e == 0 ? sn : cs));
    } else {                                  // A4 [256x512], rows 2r+d, E+(k1 r/256)
      int j = idx - 655360;
      int col = j & 511, row = j >> 9;
      int r = row >> 1, d = row & 1, k1 = col >> 1, e = col & 1;
      float th = (float)((k1 * r) & 255) * w256;
      float sn, cs; __sincosf(th, &sn, &cs);
      A4[j] = f2bf(d == 0 ? (e == 0 ? cs : -sn) : (e == 0 ? sn : cs));
    }
  } else if (bid < 4096) {                    // Zp[(s*256+c)][r] packed bf16 pair
    int b2 = bid - 3072;                      // 1024 blocks: (s, r-chunk of 16)
    int s = b2 >> 3, rq = b2 & 7;
    const float* x0 = x + (size_t)(2 * s) * 32768;
    const float* x1 = x0 + 32768;
    uint32_t v[16];
    #pragma unroll
    for (int rr = 0; rr < 16; ++rr) {
      int t = tid + 256 * (rq * 16 + rr);
      v[rr] = (uint32_t)f2bf(x0[t]) | ((uint32_t)f2bf(x1[t]) << 16);
    }
    uint32_t* dst = Zp + (size_t)(s * 256 + tid) * 128 + rq * 16;
    #pragma unroll
    for (int j = 0; j < 16; j += 4)
      *(uint4*)(dst + j) = make_uint4(v[j], v[j + 1], v[j + 2], v[j + 3]);
  } else if (bid < 4352) {                    // Gw[k1][c], fp32, root-table loop
    int k1 = bid - 4096, c = tid;
    { float sn, cs; __sincosf((float)tid * w256, &sn, &cs);
      roots[tid] = make_float2(cs, sn); }     // identical values to __sincosf(j*w256)
    __syncthreads();
    float ar = 0.f, ai = 0.f;
    for (int r = 0; r < 128; ++r) {
      float v = filt[c + 256 * r];
      float2 wv = roots[(k1 * r) & 255];      // wave-uniform -> LDS broadcast
      ar += v * wv.x; ai -= v * wv.y;
    }
    float th = (float)((k1 * c) & 65535) * (TWO_PI / 65536.0f);
    float sn, cs; __sincosf(th, &sn, &cs);
    Gw[(k1 << 8) + c] = make_float2(ar * cs + ai * sn, ai * cs - ar * sn);
  } else {                                    // Tw[k1][c] = (cos, sin) of k1*c/65536
    int k1 = bid - 4352, c = tid;
    float th = (float)((k1 * c) & 65535) * (TWO_PI / 65536.0f);
    float sn, cs; __sincosf(th, &sn, &cs);
    Tw[(k1 << 8) + c] = make_float2(cs, sn);
  }
}

// WtT[k2][k1] = sum_c Gw[k1][c] E-(k2 c/256)   (fp32, TRANSPOSED)
__global__ __launch_bounds__(256) void prep_wb(const float2* __restrict__ Gw,
                                               float2* __restrict__ WtT) {
  __shared__ float2 roots[256];
  int k1 = blockIdx.x, k2 = threadIdx.x;
  { float sn, cs; __sincosf((float)k2 * (TWO_PI / 256.0f), &sn, &cs);
    roots[k2] = make_float2(cs, sn); }
  __syncthreads();
  float ar = 0.f, ai = 0.f;
  for (int c = 0; c < 256; ++c) {
    float2 g = Gw[(k1 << 8) + c];             // wave-uniform broadcast
    float2 wv = roots[(k2 * c) & 255];        // LDS gather
    ar += g.x * wv.x + g.y * wv.y;
    ai += g.y * wv.x - g.x * wv.y;
  }
  WtT[(k2 << 8) + k1] = make_float2(ar, ai);
}

// 128^2-tile stage (MODES 1,4): R0-proven loop, 256 threads, BK=64, 2-dbuf.
// MODE 1: *Tw(E-) -> G2[(s,k1)][c].   MODE 4: write y (scale 1/65536).
template <int MODE, int KITERS>
__global__ __launch_bounds__(256, 2) void dft_stage(
    const unsigned short* __restrict__ Af,
    const unsigned short* __restrict__ Bd,
    uint32_t* __restrict__ outp,
    float* __restrict__ yout,
    const float2* __restrict__ tab) {
  __shared__ unsigned short Sm[32768];        // As0|As1|Bs0|Bs1, 16 KB each
  constexpr int KP = KITERS * 64;

  const int mt = blockIdx.x >> 8;
  const int nt = blockIdx.x & 255;
  const int m0 = mt * 128, n0 = nt * 128;

  const int tid = threadIdx.x;
  const int w = tid >> 6, lane = tid & 63;
  const int qlo = lane & 15, qhi = lane >> 4;
  const int wr = w >> 1, wc = w & 1;
  const int r8 = lane >> 3, pl = lane & 7, sj = pl ^ r8, q3 = qlo & 7;

  floatx4 acc[4][4];
  #pragma unroll
  for (int i = 0; i < 4; ++i)
    #pragma unroll
    for (int j = 0; j < 4; ++j) acc[i][j] = (floatx4){0.f, 0.f, 0.f, 0.f};

  auto issue = [&](int it, int buf) {
    const int k0 = it * 64;
    unsigned short* Asb = Sm + buf * 8192;
    unsigned short* Bsb = Sm + 16384 + buf * 8192;
    #pragma unroll
    for (int q = 0; q < 4; ++q) {
      const int R = w * 32 + q * 8 + r8;
      const unsigned short* gA = Af + (size_t)(m0 + R) * KP + k0 + sj * 8;
      const unsigned short* gB = Bd + (size_t)(n0 + R) * KP + k0 + sj * 8;
      __builtin_amdgcn_global_load_lds(
          (const __attribute__((address_space(1))) uint32_t*)gA,
          (__attribute__((address_space(3))) uint32_t*)&Asb[(w * 32 + q * 8) * 64], 16, 0, 0);
      __builtin_amdgcn_global_load_lds(
          (const __attribute__((address_space(1))) uint32_t*)gB,
          (__attribute__((address_space(3))) uint32_t*)&Bsb[(w * 32 + q * 8) * 64], 16, 0, 0);
    }
  };

  issue(0, 0);
  for (int it = 0; it < KITERS; ++it) {
    __syncthreads();                          // drains prev iter's prefetch (vmcnt)
    if (it + 1 < KITERS) issue(it + 1, (it + 1) & 1);
    const unsigned short* Ab = Sm + (it & 1) * 8192;
    const unsigned short* Bb = Sm + 16384 + (it & 1) * 8192;
    #pragma unroll
    for (int ks = 0; ks < 2; ++ks) {
      short8 a[4], bb[4];
      #pragma unroll
      for (int im = 0; im < 4; ++im) {
        const int R = wr * 64 + im * 16 + qlo;
        a[im] = *(const short8*)&Ab[R * 64 + (((ks * 4 + qhi) ^ q3) << 3)];
      }
      #pragma unroll
      for (int in = 0; in < 4; ++in) {
        const int R = wc * 64 + in * 16 + qlo;
        bb[in] = *(const short8*)&Bb[R * 64 + (((ks * 4 + qhi) ^ q3) << 3)];
      }
      #pragma unroll
      for (int im = 0; im < 4; ++im)
        #pragma unroll
        for (int in = 0; in < 4; ++in)
          acc[im][in] = __builtin_amdgcn_mfma_f32_16x16x32_bf16(a[im], bb[in], acc[im][in], 0, 0, 0);
    }
  }

  const int s_idx = n0 >> 8;                  // block-constant
  const int cl0 = n0 & 255;

  #pragma unroll
  for (int im = 0; im < 4; ++im) {
    const int mloc = wr * 32 + im * 8 + qhi * 2;
    #pragma unroll
    for (int in = 0; in < 4; ++in) {
      const int nloc = wc * 64 + in * 16 + qlo;
      const int cloc = cl0 + nloc;
      #pragma unroll
      for (int pp = 0; pp < 2; ++pp) {
        const int mC = (m0 >> 1) + mloc + pp;
        float re = acc[im][in][2 * pp], iv = acc[im][in][2 * pp + 1];
        if (MODE == 1) {
          float2 tw = tab[(mC << 8) + cloc];            // E- table (coalesced)
          float r2 = re * tw.x + iv * tw.y, i2 = iv * tw.x - re * tw.y;
          outp[(size_t)((s_idx << 8) + mC) * 256 + cloc] = packbf(r2, i2);
        } else {                                        // MODE 4: final y
          const float sc = 1.0f / 65536.0f;
          float* y0 = yout + ((size_t)s_idx << 16) + (mC << 8) + cloc;
          y0[0] = re * sc;        // y[2s][c+256r]
          y0[32768] = iv * sc;    // y[2s+1][c+256r]
        }
      }
    }
  }
}

// FUSED stages 2+3.  Block = (s in [0,128)) x (k1-quarter q in [0,4)), 512 thr.
// GEMM1: C2[m=2k2+d][n=k1l] = sum_{k=2c+e} A2[m][k] * G2[(s,k1)][k]
//   (A2 fragments read DIRECTLY from global -- 512 KB, L2-hot, shared by all
//    blocks; G2 B-tile double-buffer-staged in LDS, proven swizzle).
// Twiddle *WtT -> pack bf16 -> Pb in LDS (64 k1-rows x 256 k2-u32, XOR-swz).
// GEMM2: C3[m'=2c+d][n'=k1l] = sum_{k'=2k2+e} A3[m'][k'] * Pb[n'][k']
//   (A3 from global, B from LDS Pb: NO staging, NO barriers).
// Epilogue *Tw(E+) -> H2[(s,c)][k1].  Contraction order (chunks asc, ks asc)
// and all twiddle formulas identical to the unfused path -> bit-identical.
__global__ __launch_bounds__(512) void dft_stage23(
    const unsigned short* __restrict__ A2,
    const unsigned short* __restrict__ A3,
    const unsigned short* __restrict__ G2s,
    uint32_t* __restrict__ H2u,
    const float2* __restrict__ WtT,
    const float2* __restrict__ Tw) {
  __shared__ unsigned short Bst[2][4096];     // G2 B-tile dbuf: 2 x 8 KB
  __shared__ uint32_t Pbu[64 * 256];          // P-tile: 64 KB

  const int s  = blockIdx.x >> 2;
  const int q  = blockIdx.x & 3;
  const int k1base = q * 64;

  const int tid = threadIdx.x;
  const int w = tid >> 6, lane = tid & 63;
  const int qlo = lane & 15, qhi = lane >> 4;
  const int wr = w >> 1, wc = w & 1;          // 4m x 2n wave grid
  // B-staging lane constants
  const int srow = tid >> 3;                  // tile row 0..63
  const int spl = tid & 7;
  const int skoff = (spl ^ (srow & 7)) << 3;  // pre-swizzled global k-offset

  floatx4 acc[8][2];
  #pragma unroll
  for (int i = 0; i < 8; ++i)
    #pragma unroll
    for (int j = 0; j < 2; ++j) acc[i][j] = (floatx4){0.f, 0.f, 0.f, 0.f};

  const unsigned short* G2base = G2s + (size_t)(s * 256 + k1base) * 512;

  auto issueB = [&](int kc) {
    const unsigned short* gB = G2base + (size_t)srow * 512 + kc * 64 + skoff;
    __builtin_amdgcn_global_load_lds(
        (const __attribute__((address_space(1))) uint32_t*)gB,
        (__attribute__((address_space(3))) uint32_t*)&Bst[kc & 1][w * 512], 16, 0, 0);
  };

  // ---- GEMM1 over c (K=512, 8 chunks of 64) ----
  issueB(0);
  for (int kc = 0; kc < 8; ++kc) {
    __syncthreads();                          // chunk kc staged & visible
    if (kc + 1 < 8) issueB(kc + 1);
    const unsigned short* Bb = Bst[kc & 1];
    #pragma unroll
    for (int ks = 0; ks < 2; ++ks) {
      short8 a[8], bb[2];
      #pragma unroll
      for (int im = 0; im < 8; ++im) {
        const int R = wr * 128 + im * 16 + qlo;
        a[im] = *(const short8*)&A2[(size_t)R * 512 + kc * 64 + ks * 32 + qhi * 8];
      }
      #pragma unroll
      for (int in = 0; in < 2; ++in) {
        const int R = wc * 32 + in * 16 + qlo;
        bb[in] = *(const short8*)&Bb[R * 64 + (((ks * 4 + qhi) ^ (R & 7)) << 3)];
      }
      #pragma unroll
      for (int im = 0; im < 8; ++im)
        #pragma unroll
        for (int in = 0; in < 2; ++in)
          acc[im][in] = __builtin_amdgcn_mfma_f32_16x16x32_bf16(a[im], bb[in], acc[im][in], 0, 0, 0);
    }
  }

  // ---- twiddle (*WtT) + pack -> Pb (XOR-swizzled) ----
  #pragma unroll
  for (int im = 0; im < 8; ++im) {
    const int k2b = wr * 64 + im * 8 + qhi * 2;
    #pragma unroll
    for (int in = 0; in < 2; ++in) {
      const int k1l = wc * 32 + in * 16 + qlo;
      const int k1g = k1base + k1l;
      #pragma unroll
      for (int pp = 0; pp < 2; ++pp) {
        const int k2 = k2b + pp;
        float re = acc[im][in][2 * pp], iv = acc[im][in][2 * pp + 1];
        float2 wv = WtT[(k2 << 8) + k1g];
        float r2 = re * wv.x - iv * wv.y, i2 = re * wv.y + iv * wv.x;
        const int colsw = (((k2 >> 2) ^ (k1l & 7)) << 2) | (k2 & 3);
        Pbu[k1l * 256 + colsw] = packbf(r2, i2);
      }
    }
  }
  __syncthreads();                            // Pb complete, visible to all

  // ---- GEMM2 over k2 (K=512, 8 chunks; B from LDS Pb, barrier-free) ----
  #pragma unroll
  for (int i = 0; i < 8; ++i)
    #pragma unroll
    for (int j = 0; j < 2; ++j) acc[i][j] = (floatx4){0.f, 0.f, 0.f, 0.f};

  for (int kc = 0; kc < 8; ++kc) {
    #pragma unroll
    for (int ks = 0; ks < 2; ++ks) {
      short8 a[8], bb[2];
      const int kg = kc * 8 + ks * 4 + qhi;   // k2-quad group 0..63
      #pragma unroll
      for (int im = 0; im < 8; ++im) {
        const int R = wr * 128 + im * 16 + qlo;
        a[im] = *(const short8*)&A3[(size_t)R * 512 + kc * 64 + ks * 32 + qhi * 8];
      }
      #pragma unroll
      for (int in = 0; in < 2; ++in) {
        const int R = wc * 32 + in * 16 + qlo;
        bb[in] = *(const short8*)&Pbu[R * 256 + ((kg ^ (R & 7)) << 2)];
      }
      #pragma unroll
      for (int im = 0; im < 8; ++im)
        #pragma unroll
        for (int in = 0; in < 2; ++in)
          acc[im][in] = __builtin_amdgcn_mfma_f32_16x16x32_bf16(a[im], bb[in], acc[im][in], 0, 0, 0);
    }
  }

  // ---- epilogue (*Tw, E+) -> H2[(s,c)][k1] ----
  #pragma unroll
  for (int im = 0; im < 8; ++im) {
    const int cb = wr * 64 + im * 8 + qhi * 2;
    #pragma unroll
    for (int in = 0; in < 2; ++in) {
      const int k1l = wc * 32 + in * 16 + qlo;
      const int k1g = k1base + k1l;
      #pragma unroll
      for (int pp = 0; pp < 2; ++pp) {
        const int c = cb + pp;
        float re = acc[im][in][2 * pp], iv = acc[im][in][2 * pp + 1];
        float2 tw = Tw[(c << 8) + k1g];
        float r2 = re * tw.x - iv * tw.y, i2 = iv * tw.x + re * tw.y;
        H2u[(size_t)((s << 8) + c) * 256 + k1g] = packbf(r2, i2);
      }
    }
  }
}

extern "C" void kernel_launch(void* const* d_in, const int* in_sizes, int n_in,
                              void* d_out, int out_size, void* d_ws, size_t ws_size,
                              hipStream_t stream) {
  const float* x = (const float*)d_in[0];     // [256][32768] fp32
  const float* filt = (const float*)d_in[1];  // [1][32768] fp32
  float* Y = (float*)d_out;                   // [256][32768] fp32

  char* ws = (char*)d_ws;
  unsigned short* A1 = (unsigned short*)(ws + 0);              // 256 KB
  unsigned short* A2 = (unsigned short*)(ws + 0x40000);        // 512 KB
  unsigned short* A3 = (unsigned short*)(ws + 0xC0000);        // 512 KB
  unsigned short* A4 = (unsigned short*)(ws + 0x140000);       // 256 KB
  float2* Gw  = (float2*)(ws + 0x180000);                      // 512 KB
  float2* WtT = (float2*)(ws + 0x200000);                      // 512 KB
  float2* Tw  = (float2*)(ws + 0x280000);                      // 512 KB
  unsigned short* Zp = (unsigned short*)(ws + (3u << 20));     // 16 MB  [3,19)
  unsigned short* G2 = (unsigned short*)(ws + 19922944u);      // 32 MB  [19,51)
  unsigned short* H2 = (unsigned short*)(ws + 53477376u);      // 32 MB  [51,83)
                                                               // (old P slot; must
                                                               //  NOT alias G2 --
                                                               //  read concurrently)

  hipLaunchKernelGGL(prep_all, dim3(4608), dim3(256), 0, stream,
                     x, filt, A1, A2, A3, A4, (uint32_t*)Zp, Gw, Tw);
  hipLaunchKernelGGL(prep_wb, dim3(256), dim3(256), 0, stream, Gw, WtT);

  hipLaunchKernelGGL((dft_stage<1, 4>), dim3(1024), dim3(256), 0, stream,
                     A1, Zp, (uint32_t*)G2, (float*)nullptr, Tw);
  hipLaunchKernelGGL(dft_stage23, dim3(512), dim3(512), 0, stream,
                     A2, A3, G2, (uint32_t*)H2, WtT, Tw);
  hipLaunchKernelGGL((dft_stage<4, 8>), dim3(512), dim3(256), 0, stream,
                     A4, H2, (uint32_t*)nullptr, Y, Tw);
}

// Round 7
// 197.704 us; speedup vs baseline: 1.4430x; 1.4430x over previous
//
#include <hip/hip_runtime.h>
#include <cstdint>

typedef __attribute__((ext_vector_type(8))) short short8;
typedef __attribute__((ext_vector_type(4))) float floatx4;

#define TWO_PI 6.283185307179586f

__device__ __forceinline__ unsigned short f2bf(float f) {
  union { float f; uint32_t u; } c; c.f = f;
  uint32_t u = c.u;
  u += 0x7FFFu + ((u >> 16) & 1u);   // RNE
  return (unsigned short)(u >> 16);
}
__device__ __forceinline__ uint32_t packbf(float re, float im) {
  return (uint32_t)f2bf(re) | ((uint32_t)f2bf(im) << 16);
}

// ---------------------------------------------------------------------------
// Four-step DFT convolution, N = 65536 = 256 x 256, t = c + 256 r, k = k1+256k2.
// z_s = x[2s] + i x[2s+1].  All stages are real bf16 MFMA GEMMs (2x2 rotation
// embedding).  EVERYTHING (twiddle A-matrices AND all intermediates) is stored
// in MFMA FRAGMENT-MAJOR order:
//   frag(M16, kc, ks): 64 lanes x 16 B contiguous;
//   lane(qlo,qhi) holds  Mrow = M16*16+qlo,  k-shorts kc*64+ks*32+qhi*8 ..+8
//   (= u32 cols kc*32+ks*16+qhi*4 ..+4 for packed data).
// K-loops are therefore pure register GEMMs: coalesced global_load_dwordx4 ->
// MFMA, NO LDS, NO barriers.  Fragment values and MFMA order are identical to
// the proven staged loop -> bit-identical results.
// ---------------------------------------------------------------------------

// prep: [0,512) A1f; [512,1536) A2f; [1536,2560) A3f; [2560,3072) A4f;
// [3072,4096) x -> Zp frag-major; [4096,4352) Gw; [4352,4608) Tw.
__global__ __launch_bounds__(256) void prep_all(
    const float* __restrict__ x, const float* __restrict__ filt,
    unsigned short* __restrict__ A1, unsigned short* __restrict__ A2,
    unsigned short* __restrict__ A3, unsigned short* __restrict__ A4,
    uint32_t* __restrict__ Zp, float2* __restrict__ Gw,
    float2* __restrict__ Tw) {
  __shared__ float2 roots[256];
  const int bid = blockIdx.x;
  const int tid = threadIdx.x;
  const float w256 = TWO_PI / 256.0f;
  if (bid < 3072) {
    // fragment-major position -> (row, col) -> original twiddle value
    if (bid < 512) {                          // A1 [512 rows=2k1+d][256 k=2r+e]
      int j = bid * 256 + tid;
      int jj = j & 7, ln = (j >> 3) & 63, ks = (j >> 9) & 1;
      int t = j >> 10, M16 = t & 31, kc = t >> 5;
      int row = M16 * 16 + (ln & 15);
      int col = kc * 64 + ks * 32 + (ln >> 4) * 8 + jj;
      int k1 = row >> 1, d = row & 1, r = col >> 1, e = col & 1;
      float th = (float)((k1 * r) & 255) * w256;
      float sn, cs; __sincosf(th, &sn, &cs);
      A1[j] = f2bf(d == 0 ? (e == 0 ? cs : sn) : (e == 0 ? -sn : cs));
    } else if (bid < 1536) {                  // A2 [512 rows=2k2+d][512 k=2c+e], E-
      int j = (bid - 512) * 256 + tid;
      int jj = j & 7, ln = (j >> 3) & 63, ks = (j >> 9) & 1;
      int t = j >> 10, M16 = t & 31, kc = t >> 5;
      int row = M16 * 16 + (ln & 15);
      int col = kc * 64 + ks * 32 + (ln >> 4) * 8 + jj;
      int k2 = row >> 1, d = row & 1, cc = col >> 1, e = col & 1;
      float th = (float)((k2 * cc) & 255) * w256;
      float sn, cs; __sincosf(th, &sn, &cs);
      A2[j] = f2bf(d == 0 ? (e == 0 ? cs : sn) : (e == 0 ? -sn : cs));
    } else if (bid < 2560) {                  // A3 [512 rows=2c+d][512 k=2k2+e], E+
      int j = (bid - 1536) * 256 + tid;
      int jj = j & 7, ln = (j >> 3) & 63, ks = (j >> 9) & 1;
      int t = j >> 10, M16 = t & 31, kc = t >> 5;
      int row = M16 * 16 + (ln & 15);
      int col = kc * 64 + ks * 32 + (ln >> 4) * 8 + jj;
      int cc = row >> 1, d = row & 1, k2 = col >> 1, e = col & 1;
      float th = (float)((k2 * cc) & 255) * w256;
      float sn, cs; __sincosf(th, &sn, &cs);
      A3[j] = f2bf(d == 0 ? (e == 0 ? cs : -sn) : (e == 0 ? sn : cs));
    } else {                                  // A4 [256 rows=2r+d][512 k=2k1+e], E+
      int j = (bid - 2560) * 256 + tid;
      int jj = j & 7, ln = (j >> 3) & 63, ks = (j >> 9) & 1;
      int t = j >> 10, M16 = t & 15, kc = t >> 4;
      int row = M16 * 16 + (ln & 15);
      int col = kc * 64 + ks * 32 + (ln >> 4) * 8 + jj;
      int r = row >> 1, d = row & 1, k1 = col >> 1, e = col & 1;
      float th = (float)((k1 * r) & 255) * w256;
      float sn, cs; __sincosf(th, &sn, &cs);
      A4[j] = f2bf(d == 0 ? (e == 0 ? cs : -sn) : (e == 0 ? sn : cs));
    }
  } else if (bid < 4096) {                    // Zp frag-major: per s, rows=c(256),
    int b2 = bid - 3072;                      //   u32-cols=r(128), kc in [0,4)
    int s = b2 >> 3, rq = b2 & 7;
    const float* x0 = x + (size_t)(2 * s) * 32768;
    const float* x1 = x0 + 32768;
    uint32_t v[16];
    #pragma unroll
    for (int rr = 0; rr < 16; ++rr) {
      int t = tid + 256 * (rq * 16 + rr);
      v[rr] = (uint32_t)f2bf(x0[t]) | ((uint32_t)f2bf(x1[t]) << 16);
    }
    const int kc = rq >> 1, ks = rq & 1;
    uint32_t* dst = Zp + (size_t)s * 32768 +
                    ((kc * 16 + (tid >> 4)) * 2 + ks) * 256 + (tid & 15) * 4;
    #pragma unroll
    for (int q = 0; q < 4; ++q)
      *(uint4*)(dst + q * 64) = make_uint4(v[4*q], v[4*q+1], v[4*q+2], v[4*q+3]);
  } else if (bid < 4352) {                    // Gw[k1][c], fp32, root-table loop
    int k1 = bid - 4096, c = tid;
    { float sn, cs; __sincosf((float)tid * w256, &sn, &cs);
      roots[tid] = make_float2(cs, sn); }
    __syncthreads();
    float ar = 0.f, ai = 0.f;
    for (int r = 0; r < 128; ++r) {
      float v = filt[c + 256 * r];
      float2 wv = roots[(k1 * r) & 255];
      ar += v * wv.x; ai -= v * wv.y;
    }
    float th = (float)((k1 * c) & 65535) * (TWO_PI / 65536.0f);
    float sn, cs; __sincosf(th, &sn, &cs);
    Gw[(k1 << 8) + c] = make_float2(ar * cs + ai * sn, ai * cs - ar * sn);
  } else {                                    // Tw[k1][c] = (cos, sin) k1*c/65536
    int k1 = bid - 4352, c = tid;
    float th = (float)((k1 * c) & 65535) * (TWO_PI / 65536.0f);
    float sn, cs; __sincosf(th, &sn, &cs);
    Tw[(k1 << 8) + c] = make_float2(cs, sn);
  }
}

// WtT[k2][k1] = sum_c Gw[k1][c] E-(k2 c/256)   (fp32, TRANSPOSED)
__global__ __launch_bounds__(256) void prep_wb(const float2* __restrict__ Gw,
                                               float2* __restrict__ WtT) {
  __shared__ float2 roots[256];
  int k1 = blockIdx.x, k2 = threadIdx.x;
  { float sn, cs; __sincosf((float)k2 * (TWO_PI / 256.0f), &sn, &cs);
    roots[k2] = make_float2(cs, sn); }
  __syncthreads();
  float ar = 0.f, ai = 0.f;
  for (int c = 0; c < 256; ++c) {
    float2 g = Gw[(k1 << 8) + c];
    float2 wv = roots[(k2 * c) & 255];
    ar += g.x * wv.x + g.y * wv.y;
    ai += g.y * wv.x - g.x * wv.y;
  }
  WtT[(k2 << 8) + k1] = make_float2(ar, ai);
}

// Register-GEMM DFT stage.  Tile 128x128, 4 waves (2m x 2n), acc[4][4].
// A (frag-major shorts), B (frag-major u32 pairs, per-s KC*8192 u32).
// K-loop: coalesced dwordx4 loads -> MFMA.  No LDS, no barriers.
// Epilogue: twiddle -> LDS transpose -> next stage's frag-major layout.
// MODE 1: *Tw(E-) -> G2f.  MODE 2: *WtT -> Pf.  MODE 3: *Tw(E+) -> H2f.
// MODE 4: y directly.
template <int MODE, int KC, int MD16>
__global__ __launch_bounds__(256, 2) void dft_stageR(
    const unsigned short* __restrict__ Af,
    const uint32_t* __restrict__ Bf,
    uint32_t* __restrict__ outp,
    float* __restrict__ yout,
    const float2* __restrict__ tab) {
  __shared__ uint32_t Tr[(MODE == 4) ? 64 : 8704];  // transpose buf (<=34.8 KB)

  const int mt = blockIdx.x >> 8;
  const int nt = blockIdx.x & 255;
  const int m0 = mt * 128, n0 = nt * 128;
  const int s = n0 >> 8;                      // batch-pair index
  const int nlow = n0 & 255;                  // c- or k1- offset within s

  const int tid = threadIdx.x;
  const int w = tid >> 6, lane = tid & 63;
  const int qlo = lane & 15, qhi = lane >> 4;
  const int wr = w >> 1, wc = w & 1;

  floatx4 acc[4][4];
  #pragma unroll
  for (int i = 0; i < 4; ++i)
    #pragma unroll
    for (int j = 0; j < 4; ++j) acc[i][j] = (floatx4){0.f, 0.f, 0.f, 0.f};

  const uint32_t* Bp = Bf + (size_t)s * (KC * 8192);
  const int m16b = (m0 >> 4) + wr * 4;
  const int n16b = (nlow >> 4) + wc * 4;

  #pragma unroll
  for (int kc = 0; kc < KC; ++kc) {
    #pragma unroll
    for (int ks = 0; ks < 2; ++ks) {
      short8 a[4], b[4];
      #pragma unroll
      for (int im = 0; im < 4; ++im)
        a[im] = *(const short8*)(Af +
            (size_t)(((kc * MD16 + m16b + im) * 2 + ks) * 512 + lane * 8));
      #pragma unroll
      for (int in = 0; in < 4; ++in)
        b[in] = *(const short8*)(Bp +
            (((kc * 16 + n16b + in) * 2 + ks) * 256 + lane * 4));
      #pragma unroll
      for (int im = 0; im < 4; ++im)
        #pragma unroll
        for (int in = 0; in < 4; ++in)
          acc[im][in] = __builtin_amdgcn_mfma_f32_16x16x32_bf16(
              a[im], b[in], acc[im][in], 0, 0, 0);
    }
  }

  if constexpr (MODE == 1) {                  // -> G2f rows=k1, u32-cols=c
    #pragma unroll
    for (int im = 0; im < 4; ++im) {
      const int mloc = wr * 32 + im * 8 + qhi * 2;
      #pragma unroll
      for (int in = 0; in < 4; ++in) {
        const int nloc = wc * 64 + in * 16 + qlo;
        const int c = nlow + nloc;
        #pragma unroll
        for (int pp = 0; pp < 2; ++pp) {
          const int k1loc = mloc + pp;
          const int k1 = (m0 >> 1) + k1loc;
          float re = acc[im][in][2*pp], iv = acc[im][in][2*pp+1];
          float2 tw = tab[(k1 << 8) + c];
          float r2 = re * tw.x + iv * tw.y, i2 = iv * tw.x - re * tw.y;
          Tr[k1loc * 132 + nloc] = packbf(r2, i2);
        }
      }
    }
    __syncthreads();
    #pragma unroll
    for (int p = 0; p < 8; ++p) {
      const int sb = p * 4 + w;
      const int kcL = sb >> 3, N16l = (sb >> 1) & 3, ksb = sb & 1;
      uint4 v = *(const uint4*)&Tr[(N16l*16 + qlo) * 132 + kcL*32 + ksb*16 + qhi*4];
      const int kcg = (nlow >> 5) + kcL, N16g = (m0 >> 5) + N16l;
      *(uint4*)&outp[(size_t)s * 65536 +
                     (size_t)(((kcg * 16 + N16g) * 2 + ksb) * 256 + lane * 4)] = v;
    }
  } else if constexpr (MODE == 2) {           // -> Pf rows=k1, u32-cols=k2
    #pragma unroll
    for (int im = 0; im < 4; ++im) {
      const int mloc = wr * 32 + im * 8 + qhi * 2;
      #pragma unroll
      for (int in = 0; in < 4; ++in) {
        const int nloc = wc * 64 + in * 16 + qlo;
        const int k1 = nlow + nloc;
        #pragma unroll
        for (int pp = 0; pp < 2; ++pp) {
          const int k2loc = mloc + pp;
          const int k2 = (m0 >> 1) + k2loc;
          float re = acc[im][in][2*pp], iv = acc[im][in][2*pp+1];
          float2 wv = tab[(k2 << 8) + k1];
          float r2 = re * wv.x - iv * wv.y, i2 = re * wv.y + iv * wv.x;
          Tr[nloc * 68 + k2loc] = packbf(r2, i2);
        }
      }
    }
    __syncthreads();
    #pragma unroll
    for (int p = 0; p < 8; ++p) {
      const int sb = p * 4 + w;
      const int kcL = sb >> 4, N16l = (sb >> 1) & 7, ksb = sb & 1;
      uint4 v = *(const uint4*)&Tr[(N16l*16 + qlo) * 68 + kcL*32 + ksb*16 + qhi*4];
      const int kcg = (m0 >> 6) + kcL, N16g = (nlow >> 4) + N16l;
      *(uint4*)&outp[(size_t)s * 65536 +
                     (size_t)(((kcg * 16 + N16g) * 2 + ksb) * 256 + lane * 4)] = v;
    }
  } else if constexpr (MODE == 3) {           // -> H2f rows=c, u32-cols=k1
    #pragma unroll
    for (int im = 0; im < 4; ++im) {
      const int mloc = wr * 32 + im * 8 + qhi * 2;
      #pragma unroll
      for (int in = 0; in < 4; ++in) {
        const int nloc = wc * 64 + in * 16 + qlo;
        const int k1 = nlow + nloc;
        #pragma unroll
        for (int pp = 0; pp < 2; ++pp) {
          const int cloc = mloc + pp;
          const int c = (m0 >> 1) + cloc;
          float re = acc[im][in][2*pp], iv = acc[im][in][2*pp+1];
          float2 tw = tab[(c << 8) + k1];
          float r2 = re * tw.x - iv * tw.y, i2 = iv * tw.x + re * tw.y;
          Tr[cloc * 132 + nloc] = packbf(r2, i2);
        }
      }
    }
    __syncthreads();
    #pragma unroll
    for (int p = 0; p < 8; ++p) {
      const int sb = p * 4 + w;
      const int kcL = sb >> 3, N16l = (sb >> 1) & 3, ksb = sb & 1;
      uint4 v = *(const uint4*)&Tr[(N16l*16 + qlo) * 132 + kcL*32 + ksb*16 + qhi*4];
      const int kcg = (nlow >> 5) + kcL, N16g = (m0 >> 5) + N16l;
      *(uint4*)&outp[(size_t)s * 65536 +
                     (size_t)(((kcg * 16 + N16g) * 2 + ksb) * 256 + lane * 4)] = v;
    }
  } else {                                    // MODE 4: final y
    #pragma unroll
    for (int im = 0; im < 4; ++im) {
      const int mloc = wr * 32 + im * 8 + qhi * 2;
      #pragma unroll
      for (int in = 0; in < 4; ++in) {
        const int nloc = wc * 64 + in * 16 + qlo;
        const int cloc = nlow + nloc;
        #pragma unroll
        for (int pp = 0; pp < 2; ++pp) {
          const int mC = (m0 >> 1) + mloc + pp;
          float re = acc[im][in][2*pp], iv = acc[im][in][2*pp+1];
          const float sc = 1.0f / 65536.0f;
          float* y0 = yout + ((size_t)s << 16) + (mC << 8) + cloc;
          y0[0] = re * sc;        // y[2s][c+256r]
          y0[32768] = iv * sc;    // y[2s+1][c+256r]
        }
      }
    }
  }
}

extern "C" void kernel_launch(void* const* d_in, const int* in_sizes, int n_in,
                              void* d_out, int out_size, void* d_ws, size_t ws_size,
                              hipStream_t stream) {
  const float* x = (const float*)d_in[0];     // [256][32768] fp32
  const float* filt = (const float*)d_in[1];  // [1][32768] fp32
  float* Y = (float*)d_out;                   // [256][32768] fp32

  char* ws = (char*)d_ws;
  unsigned short* A1 = (unsigned short*)(ws + 0);              // 256 KB
  unsigned short* A2 = (unsigned short*)(ws + 0x40000);        // 512 KB
  unsigned short* A3 = (unsigned short*)(ws + 0xC0000);        // 512 KB
  unsigned short* A4 = (unsigned short*)(ws + 0x140000);       // 256 KB
  float2* Gw  = (float2*)(ws + 0x180000);                      // 512 KB
  float2* WtT = (float2*)(ws + 0x200000);                      // 512 KB
  float2* Tw  = (float2*)(ws + 0x280000);                      // 512 KB
  uint32_t* Zp = (uint32_t*)(ws + (3u << 20));                 // 16 MB  [3,19)
  uint32_t* G2 = (uint32_t*)(ws + 19922944u);                  // 32 MB  [19,51)
  uint32_t* P  = (uint32_t*)(ws + 53477376u);                  // 32 MB  [51,83)
  uint32_t* H2 = (uint32_t*)(ws + (3u << 20));                 // 32 MB, reuses
                                                               // Zp+G2 (dead)

  hipLaunchKernelGGL(prep_all, dim3(4608), dim3(256), 0, stream,
                     x, filt, A1, A2, A3, A4, Zp, Gw, Tw);
  hipLaunchKernelGGL(prep_wb, dim3(256), dim3(256), 0, stream, Gw, WtT);

  hipLaunchKernelGGL((dft_stageR<1, 4, 32>), dim3(1024), dim3(256), 0, stream,
                     A1, Zp, G2, (float*)nullptr, Tw);
  hipLaunchKernelGGL((dft_stageR<2, 8, 32>), dim3(1024), dim3(256), 0, stream,
                     A2, G2, P, (float*)nullptr, WtT);
  hipLaunchKernelGGL((dft_stageR<3, 8, 32>), dim3(1024), dim3(256), 0, stream,
                     A3, P, H2, (float*)nullptr, Tw);
  hipLaunchKernelGGL((dft_stageR<4, 8, 16>), dim3(512), dim3(256), 0, stream,
                     A4, H2, (uint32_t*)nullptr, Y, Tw);
}